// Round 5
// baseline (780.392 us; speedup 1.0000x reference)
//
#include <hip/hip_runtime.h>
#include <hip/hip_bf16.h>

#define EPS_BN 1e-5f

typedef __bf16 bf16_t;
typedef __bf16 bf16x4 __attribute__((ext_vector_type(4)));
typedef __bf16 bf16x8 __attribute__((ext_vector_type(8)));
typedef float floatx16 __attribute__((ext_vector_type(16)));

// ---------------- unified conv: stride-2 3x3 + bias + relu (+BN-fold in) ---
// Fused tails:
//  * PREP (conv1 only): blocks >= CONVBLKS run the old prep_kernel body
//    (wq build + wpack fragment packing) — saves one launch.
//  * BN finalize: each conv block publishes its partial sums, then the LAST
//    block (device-scope atomic counter) reduces partials -> scsh directly
//    (replaces the 4 fin_kernel launches). Counter self-resets for graph
//    replay; zeroed once via hipMemsetAsync before the chain.
template<int CIN, int HOUT, int OY_PER, int CO_PER, bool FOLD, bool PREP>
__global__ __launch_bounds__(256) void conv_kernel(
    const float* __restrict__ in, const float* __restrict__ scsh_in,
    const float* __restrict__ w, const float* __restrict__ bias,
    float* __restrict__ out, float* __restrict__ part_out,
    const float* __restrict__ gamma, const float* __restrict__ beta,
    float* __restrict__ scsh_out, unsigned* __restrict__ counter,
    const float* __restrict__ qv, const float* __restrict__ gw1v,
    const float* __restrict__ gb1v, const float* __restrict__ g2v,
    const float* __restrict__ g3v, const float* __restrict__ g4v,
    float* __restrict__ wqo, bf16_t* __restrict__ wpck)
{
    const int HIN = 2 * HOUT, ROWS = 2 * OY_PER + 3, RW = 2 * HOUT + 2;
    const int TILES = HOUT / OY_PER;
    const int CONVBLKS = 64 * TILES;          // B = 64
    const int WPC = (HOUT * OY_PER) / 64;     // waves per channel-group
    int t = threadIdx.x;

    if (PREP && blockIdx.x >= CONVBLKS) {
        // ---- embedded prep: wq + pack W fragments
        // wpack layout: (((layer*8+cg)*16+kt)*64+lane)*8+e ; serves as both
        // B-operand (untransposed) and A-operand (transposed) fragments.
        int blk = blockIdx.x - CONVBLKS;
        float acc = gb1v[t];
        #pragma unroll
        for (int d = 0; d < 11; d++)
            acc = fmaf(qv[blk * 11 + d], gw1v[(52 + d) * 256 + t], acc);
        wqo[blk * 256 + t] = acc;
        for (int idx = blk * 3072 + t; idx < blk * 3072 + 3072; idx += 256) {
            int layer = idx >> 16;
            int rem = idx & 65535;
            int col = rem & 255;
            int k = rem >> 8;
            const float* gw = (layer == 0) ? g2v : ((layer == 1) ? g3v : g4v);
            float v = gw[k * 256 + col];
            int cg = col >> 5, l31x = col & 31;
            int kt = k >> 4, l2x = (k >> 3) & 1, e = k & 7;
            int lane2 = l2x * 32 + l31x;
            wpck[(((layer * 8 + cg) * 16 + kt) * 64 + lane2) * 8 + e] = (bf16_t)v;
        }
        return;
    }

    int b = blockIdx.x / TILES, tile = blockIdx.x % TILES;
    int oy0 = tile * OY_PER;
    __shared__ float tin[CIN][ROWS][RW];
    __shared__ float scf[24], shf[24];
    __shared__ float red[4][CO_PER * 2];
    if (FOLD) {
        if (t < 24) { scf[t] = scsh_in[t]; shf[t] = scsh_in[24 + t]; }
        __syncthreads();
    }
    const int total = CIN * ROWS * RW;
    int iyb = 2 * oy0 - 1;
    #pragma unroll 2
    for (int idx = t; idx < total; idx += 256) {
        int rx = idx % RW;
        int rem = idx / RW;
        int ry = rem % ROWS;
        int ci = rem / ROWS;
        int iy = iyb + ry, ix = rx - 1;
        float v = 0.f;
        if ((unsigned)iy < (unsigned)HIN && (unsigned)ix < (unsigned)HIN) {
            float raw = in[(b * CIN + ci) * HIN * HIN + iy * HIN + ix];
            v = FOLD ? fmaf(raw, scf[ci], shf[ci]) : raw;
        }
        tin[ci][ry][rx] = v;
    }
    __syncthreads();
    int ox = t % HOUT;
    int oyl = (t / HOUT) % OY_PER;
    int cog = t / (HOUT * OY_PER);            // wave-uniform
    const float* wp = w + cog * CO_PER * CIN * 9;
    float acc[CO_PER];
    #pragma unroll
    for (int r = 0; r < CO_PER; r++) acc[r] = bias[cog * CO_PER + r];
    for (int ci = 0; ci < CIN; ci++)
        #pragma unroll
        for (int ky = 0; ky < 3; ky++)
            #pragma unroll
            for (int kx = 0; kx < 3; kx++) {
                float v = tin[ci][2 * oyl + ky][2 * ox + kx];
                #pragma unroll
                for (int r = 0; r < CO_PER; r++)
                    acc[r] = fmaf(v, wp[(r * CIN + ci) * 9 + ky * 3 + kx], acc[r]);
            }
    int oy = oy0 + oyl;
    float s1[CO_PER], s2[CO_PER];
    #pragma unroll
    for (int r = 0; r < CO_PER; r++) {
        float v = fmaxf(acc[r], 0.f);
        out[((b * 24 + cog * CO_PER + r) * HOUT + oy) * HOUT + ox] = v;
        s1[r] = v;
        s2[r] = v * v;
    }
    int lane = t & 63, w_id = t >> 6;
    #pragma unroll
    for (int r = 0; r < CO_PER; r++) {
        float a = s1[r], c2 = s2[r];
        #pragma unroll
        for (int off = 32; off > 0; off >>= 1) {
            a += __shfl_xor(a, off);
            c2 += __shfl_xor(c2, off);
        }
        if (lane == 0) { red[w_id][r * 2] = a; red[w_id][r * 2 + 1] = c2; }
    }
    __syncthreads();
    if (t < 48) {
        int ch = t >> 1, st = t & 1;
        int cg = ch / CO_PER, r = ch % CO_PER;
        float v = 0.f;
        #pragma unroll
        for (int k = 0; k < WPC; k++) v += red[cg * WPC + k][r * 2 + st];
        part_out[blockIdx.x * 48 + t] = v;
    }

    // ---- fused BN finalize: last block reduces all partials -> scsh
    __threadfence();                      // release this block's part writes
    __syncthreads();
    __shared__ unsigned lastflag;
    if (t == 0)
        lastflag = (atomicAdd(counter, 1u) == (unsigned)(CONVBLKS - 1)) ? 1u : 0u;
    __syncthreads();
    if (!lastflag) return;
    __threadfence();                      // acquire all blocks' part writes
    const float inv_n = 1.f / (float)(64 * HOUT * HOUT);
    int s = t % 48, chk = t / 48;         // 5 chunks of 48 (t<240 active)
    float a = 0.f;
    if (t < 240)
        for (int p = chk; p < CONVBLKS; p += 5) a += part_out[p * 48 + s];
    __shared__ float redf[5][48];
    if (t < 240) redf[chk][s] = a;
    __syncthreads();
    if (t < 24) {
        float sa = 0.f, sb = 0.f;
        #pragma unroll
        for (int k = 0; k < 5; k++) { sa += redf[k][2 * t]; sb += redf[k][2 * t + 1]; }
        float m = sa * inv_n;
        float var = sb * inv_n - m * m;
        float sc = gamma[t] * rsqrtf(var + EPS_BN);
        scsh_out[t] = sc;
        scsh_out[24 + t] = fmaf(-m, sc, beta[t]);
    }
    if (t == 0) *counter = 0;             // self-reset for graph replay
}

// ---------------- U/V with BN4 folded (scale/shift precomputed) ------------
__global__ __launch_bounds__(256) void uv_kernel(
    const float* __restrict__ x4, const float* __restrict__ scsh4,
    const float* __restrict__ gw1, float* __restrict__ U, float* __restrict__ V)
{
    int b = blockIdx.x >> 2, n0 = (blockIdx.x & 3) * 16;
    __shared__ float o[16][26];
    int t = threadIdx.x;
    for (int idx = t; idx < 16 * 26; idx += 256) {
        int n = idx / 26, f = idx % 26;
        int ng = n0 + n;
        float val;
        if (f < 24)
            val = fmaf(x4[(b * 24 + f) * 64 + ng], scsh4[f], scsh4[24 + f]);
        else if (f == 24) val = (float)(ng >> 3) * 0.125f;
        else              val = (float)(ng & 7) * 0.125f;
        o[n][f] = val;
    }
    __syncthreads();
    float g1u[26], g1v[26];
    #pragma unroll
    for (int f = 0; f < 26; f++) {
        g1u[f] = gw1[f * 256 + t];
        g1v[f] = gw1[(26 + f) * 256 + t];
    }
    for (int n = 0; n < 16; n++) {
        float u = 0.f, v = 0.f;
        #pragma unroll
        for (int f = 0; f < 26; f++) {
            float of = o[n][f];
            u = fmaf(of, g1u[f], u);
            v = fmaf(of, g1v[f], v);
        }
        int ng = n0 + n;
        U[(b * 64 + ng) * 256 + t] = u;
        V[(b * 64 + ng) * 256 + t] = v;
    }
}

// ---------------- fused pair MLP: 256 thr, 4 waves, 2 i's (128 rows) -------
// Wave wn owns feats wn*64..+64 (2 cgs) and ALL 128 rows: W read once per
// block-layer. Layers 1-2 transposed product acc=mfma(W,h), bias in acc init.
// Software-pipelined ks-loop: W 4-deep register rotation, h 1-deep ping-pong.
__global__ __launch_bounds__(256, 2) void pair_kernel(
    const float* __restrict__ U, const float* __restrict__ V,
    const float* __restrict__ wq, const bf16_t* __restrict__ wpack,
    const float* __restrict__ gb2, const float* __restrict__ gb3,
    const float* __restrict__ gb4, float* __restrict__ partial)
{
    __shared__ __align__(16) bf16_t hA[128][264];
    int blk = blockIdx.x;
    int b = blk >> 5;
    int i0 = (blk & 31) * 2;
    int t = threadIdx.x;

    // ---- build h1: thread covers 4 feats x 16 j x 2 i, float4 loads + b64 LDS writes
    {
        int c4 = (t & 63) * 4;
        int jh = t >> 6;                  // 0..3
        float4 wq4 = *(const float4*)(wq + b * 256 + c4);
        float4 u0 = *(const float4*)(U + (b * 64 + i0) * 256 + c4);
        float4 u1 = *(const float4*)(U + (b * 64 + i0 + 1) * 256 + c4);
        u0.x += wq4.x; u0.y += wq4.y; u0.z += wq4.z; u0.w += wq4.w;
        u1.x += wq4.x; u1.y += wq4.y; u1.z += wq4.z; u1.w += wq4.w;
        const float* Vb = V + (b * 64) * 256 + c4;
        for (int j = jh * 16; j < jh * 16 + 16; j++) {
            float4 v = *(const float4*)(Vb + j * 256);
            bf16x4 h0, h1;
            h0[0] = (bf16_t)fmaxf(u0.x + v.x, 0.f);
            h0[1] = (bf16_t)fmaxf(u0.y + v.y, 0.f);
            h0[2] = (bf16_t)fmaxf(u0.z + v.z, 0.f);
            h0[3] = (bf16_t)fmaxf(u0.w + v.w, 0.f);
            h1[0] = (bf16_t)fmaxf(u1.x + v.x, 0.f);
            h1[1] = (bf16_t)fmaxf(u1.y + v.y, 0.f);
            h1[2] = (bf16_t)fmaxf(u1.z + v.z, 0.f);
            h1[3] = (bf16_t)fmaxf(u1.w + v.w, 0.f);
            *(bf16x4*)&hA[j][c4] = h0;
            *(bf16x4*)&hA[64 + j][c4] = h1;
        }
    }
    __syncthreads();

    int lane = t & 63, wn = t >> 6;       // 4 waves
    int l31 = lane & 31, l2 = lane >> 5;

    // ======== layers 1,2: transposed-output, wave = 128 rows x 64 feats
    #pragma unroll 1
    for (int layer = 0; layer < 2; layer++) {
        const float* bias = (layer == 0) ? gb2 : gb3;
        const bf16_t* W0 = wpack + ((size_t)((layer * 8 + wn * 2) * 1024) + lane) * 8;
        const bf16_t* W1 = W0 + 8192;

        // bias folded into acc init: transposed D reg = out-feat
        floatx16 acc[4][2];
        #pragma unroll
        for (int nt = 0; nt < 2; nt++) {
            int fb = (wn * 2 + nt) * 32 + 4 * l2;
            #pragma unroll
            for (int g = 0; g < 4; g++) {
                float4 bv = *(const float4*)(bias + fb + 8 * g);
                acc[0][nt][4 * g + 0] = bv.x;
                acc[0][nt][4 * g + 1] = bv.y;
                acc[0][nt][4 * g + 2] = bv.z;
                acc[0][nt][4 * g + 3] = bv.w;
            }
            #pragma unroll
            for (int mt = 1; mt < 4; mt++) acc[mt][nt] = acc[0][nt];
        }

        bf16x8 Wb0[4], Wb1[4];
        #pragma unroll
        for (int p = 0; p < 4; p++) {
            Wb0[p] = *(const bf16x8*)(W0 + p * 512);
            Wb1[p] = *(const bf16x8*)(W1 + p * 512);
        }
        bf16x8 hb[2][4];
        #pragma unroll
        for (int mt = 0; mt < 4; mt++)
            hb[0][mt] = *(const bf16x8*)&hA[mt * 32 + l31][l2 * 8];

        #pragma unroll
        for (int ks = 0; ks < 16; ks++) {
            if (ks < 15) {
                #pragma unroll
                for (int mt = 0; mt < 4; mt++)
                    hb[(ks + 1) & 1][mt] =
                        *(const bf16x8*)&hA[mt * 32 + l31][(ks + 1) * 16 + l2 * 8];
            }
            #pragma unroll
            for (int mt = 0; mt < 4; mt++) {
                acc[mt][0] = __builtin_amdgcn_mfma_f32_32x32x16_bf16(Wb0[ks & 3], hb[ks & 1][mt], acc[mt][0], 0, 0, 0);
                acc[mt][1] = __builtin_amdgcn_mfma_f32_32x32x16_bf16(Wb1[ks & 3], hb[ks & 1][mt], acc[mt][1], 0, 0, 0);
            }
            if (ks + 4 < 16) {
                Wb0[ks & 3] = *(const bf16x8*)(W0 + (ks + 4) * 512);
                Wb1[ks & 3] = *(const bf16x8*)(W1 + (ks + 4) * 512);
            }
        }

        __syncthreads();
        #pragma unroll
        for (int mt = 0; mt < 4; mt++) {
            int row = mt * 32 + l31;
            #pragma unroll
            for (int nt = 0; nt < 2; nt++) {
                int fb = (wn * 2 + nt) * 32 + 4 * l2;
                #pragma unroll
                for (int g = 0; g < 4; g++) {
                    bf16x4 w4;
                    w4[0] = (bf16_t)fmaxf(acc[mt][nt][4 * g + 0], 0.f);
                    w4[1] = (bf16_t)fmaxf(acc[mt][nt][4 * g + 1], 0.f);
                    w4[2] = (bf16_t)fmaxf(acc[mt][nt][4 * g + 2], 0.f);
                    w4[3] = (bf16_t)fmaxf(acc[mt][nt][4 * g + 3], 0.f);
                    *(bf16x4*)&hA[row][fb + 8 * g] = w4;
                }
            }
        }
        __syncthreads();
    }

    // ======== layer 3: untransposed (lane = out-col) + register reduction
    {
        floatx16 acc[4][2];
        #pragma unroll
        for (int nt = 0; nt < 2; nt++) {
            float bc = gb4[wn * 64 + nt * 32 + l31];
            #pragma unroll
            for (int mt = 0; mt < 4; mt++)
                #pragma unroll
                for (int reg = 0; reg < 16; reg++)
                    acc[mt][nt][reg] = bc;
        }

        const bf16_t* W0 = wpack + ((size_t)((16 + wn * 2) * 1024) + lane) * 8;
        const bf16_t* W1 = W0 + 8192;

        bf16x8 Wb0[4], Wb1[4];
        #pragma unroll
        for (int p = 0; p < 4; p++) {
            Wb0[p] = *(const bf16x8*)(W0 + p * 512);
            Wb1[p] = *(const bf16x8*)(W1 + p * 512);
        }
        bf16x8 hb[2][4];
        #pragma unroll
        for (int mt = 0; mt < 4; mt++)
            hb[0][mt] = *(const bf16x8*)&hA[mt * 32 + l31][l2 * 8];

        #pragma unroll
        for (int ks = 0; ks < 16; ks++) {
            if (ks < 15) {
                #pragma unroll
                for (int mt = 0; mt < 4; mt++)
                    hb[(ks + 1) & 1][mt] =
                        *(const bf16x8*)&hA[mt * 32 + l31][(ks + 1) * 16 + l2 * 8];
            }
            #pragma unroll
            for (int mt = 0; mt < 4; mt++) {
                acc[mt][0] = __builtin_amdgcn_mfma_f32_32x32x16_bf16(hb[ks & 1][mt], Wb0[ks & 3], acc[mt][0], 0, 0, 0);
                acc[mt][1] = __builtin_amdgcn_mfma_f32_32x32x16_bf16(hb[ks & 1][mt], Wb1[ks & 3], acc[mt][1], 0, 0, 0);
            }
            if (ks + 4 < 16) {
                Wb0[ks & 3] = *(const bf16x8*)(W0 + (ks + 4) * 512);
                Wb1[ks & 3] = *(const bf16x8*)(W1 + (ks + 4) * 512);
            }
        }

        #pragma unroll
        for (int nt = 0; nt < 2; nt++) {
            float s = 0.f;
            #pragma unroll
            for (int mt = 0; mt < 4; mt++)
                #pragma unroll
                for (int reg = 0; reg < 16; reg++)
                    s += fmaxf(acc[mt][nt][reg], 0.0f);
            s += __shfl_xor(s, 32);
            if (l2 == 0)
                partial[blk * 256 + wn * 64 + nt * 32 + l31] = s;
        }
    }
}

// ---------------- f_phi ----------------
__global__ __launch_bounds__(256) void fphi_kernel(
    const float* __restrict__ partial,
    const float* __restrict__ fw1, const float* __restrict__ fb1,
    const float* __restrict__ fw2, const float* __restrict__ fb2,
    const float* __restrict__ fw3, const float* __restrict__ fb3,
    float* __restrict__ out)
{
    int b = blockIdx.x, t = threadIdx.x;
    __shared__ float g[256], h1[256], h2[256];
    float s = 0.f;
    for (int k = 0; k < 32; k++) s += partial[(b * 32 + k) * 256 + t];
    g[t] = s * (1.0f / 4096.0f);
    __syncthreads();
    float a1 = fb1[t];
    for (int k = 0; k < 256; k++) a1 = fmaf(g[k], fw1[k * 256 + t], a1);
    h1[t] = fmaxf(a1, 0.0f);
    __syncthreads();
    float a2 = fb2[t];
    for (int k = 0; k < 256; k++) a2 = fmaf(h1[k], fw2[k * 256 + t], a2);
    h2[t] = fmaxf(a2, 0.0f);
    __syncthreads();
    if (t < 10) {
        float a3 = fb3[t];
        for (int k = 0; k < 256; k++) a3 = fmaf(h2[k], fw3[k * 10 + t], a3);
        out[b * 10 + t] = a3;
    }
}

extern "C" void kernel_launch(void* const* d_in, const int* in_sizes, int n_in,
                              void* d_out, int out_size, void* d_ws, size_t ws_size,
                              hipStream_t stream)
{
    (void)in_sizes; (void)n_in; (void)out_size; (void)ws_size;
    const float* img = (const float*)d_in[0];
    const float* q   = (const float*)d_in[1];
    const float* cw[4] = {(const float*)d_in[2],  (const float*)d_in[6],
                          (const float*)d_in[10], (const float*)d_in[14]};
    const float* cb[4] = {(const float*)d_in[3],  (const float*)d_in[7],
                          (const float*)d_in[11], (const float*)d_in[15]};
    const float* bg[4] = {(const float*)d_in[4],  (const float*)d_in[8],
                          (const float*)d_in[12], (const float*)d_in[16]};
    const float* bbv[4] = {(const float*)d_in[5],  (const float*)d_in[9],
                           (const float*)d_in[13], (const float*)d_in[17]};
    const float* gw1 = (const float*)d_in[18]; const float* gb1 = (const float*)d_in[19];
    const float* gw2 = (const float*)d_in[20]; const float* gb2 = (const float*)d_in[21];
    const float* gw3 = (const float*)d_in[22]; const float* gb3 = (const float*)d_in[23];
    const float* gw4 = (const float*)d_in[24]; const float* gb4 = (const float*)d_in[25];
    const float* fw1 = (const float*)d_in[26]; const float* fb1 = (const float*)d_in[27];
    const float* fw2 = (const float*)d_in[28]; const float* fb2 = (const float*)d_in[29];
    const float* fw3 = (const float*)d_in[30]; const float* fb3 = (const float*)d_in[31];

    float* ws  = (float*)d_ws;
    float* x1  = ws;                      // 6291456
    float* x2  = x1 + 6291456;            // 1572864
    float* x3  = x2 + 1572864;            // 393216
    float* x4  = x3 + 393216;             // 98304
    float* U   = x4 + 98304;              // 1048576
    float* V   = U + 1048576;             // 1048576
    float* wqv = V + 1048576;             // 16384
    float* part = wqv + 16384;            // 524288
    float* p1  = part + 524288;           // 2048*48
    float* p2  = p1 + 98304;              // 1024*48
    float* p3  = p2 + 49152;              // 256*48
    float* p4  = p3 + 12288;              // 64*48
    float* scsh1 = p4 + 3072;
    float* scsh2 = scsh1 + 48;
    float* scsh3 = scsh2 + 48;
    float* scsh4 = scsh3 + 48;
    bf16_t* wpack = (bf16_t*)(scsh4 + 48);  // 3*65536 bf16
    unsigned* ctrs = (unsigned*)(wpack + 196608);  // 4 counters

    hipMemsetAsync(ctrs, 0, 4 * sizeof(unsigned), stream);

    conv_kernel<3, 64, 2, 12, false, true><<<2048 + 64, 256, 0, stream>>>(
        img, nullptr, cw[0], cb[0], x1, p1,
        bg[0], bbv[0], scsh1, ctrs + 0,
        q, gw1, gb1, gw2, gw3, gw4, wqv, wpack);
    conv_kernel<24, 32, 2, 6, true, false><<<1024, 256, 0, stream>>>(
        x1, scsh1, cw[1], cb[1], x2, p2,
        bg[1], bbv[1], scsh2, ctrs + 1,
        nullptr, nullptr, nullptr, nullptr, nullptr, nullptr, nullptr, nullptr);
    conv_kernel<24, 16, 4, 6, true, false><<<256, 256, 0, stream>>>(
        x2, scsh2, cw[2], cb[2], x3, p3,
        bg[2], bbv[2], scsh3, ctrs + 2,
        nullptr, nullptr, nullptr, nullptr, nullptr, nullptr, nullptr, nullptr);
    conv_kernel<24, 8, 8, 6, true, false><<<64, 256, 0, stream>>>(
        x3, scsh3, cw[3], cb[3], x4, p4,
        bg[3], bbv[3], scsh4, ctrs + 3,
        nullptr, nullptr, nullptr, nullptr, nullptr, nullptr, nullptr, nullptr);
    uv_kernel<<<256, 256, 0, stream>>>(x4, scsh4, gw1, U, V);
    pair_kernel<<<2048, 256, 0, stream>>>(U, V, wqv, wpack, gb2, gb3, gb4, part);
    fphi_kernel<<<64, 256, 0, stream>>>(part, fw1, fb1, fw2, fb2, fw3, fb3,
                                        (float*)d_out);
}

// Round 6
// 423.820 us; speedup vs baseline: 1.8413x; 1.8413x over previous
//
#include <hip/hip_runtime.h>
#include <hip/hip_bf16.h>

#define EPS_BN 1e-5f

typedef __bf16 bf16_t;
typedef __bf16 bf16x4 __attribute__((ext_vector_type(4)));
typedef __bf16 bf16x8 __attribute__((ext_vector_type(8)));
typedef float floatx16 __attribute__((ext_vector_type(16)));

// ---------------- prep: wq + pack W fragments ----------------
// wpack layout: (((layer*8 + cg)*16 + kt)*64 + lane)*8 + e
//   cg = col>>5 (0..7), lane = ((k>>3)&1)*32 + (col&31), k = kt*16+((k>>3)&1)*8+e
// Serves BOTH as B-operand (col=lane&31) for the untransposed product and as
// A-operand (row=lane&31) for the transposed product (layouts index-identical).
__global__ __launch_bounds__(256) void prep_kernel(
    const float* __restrict__ q, const float* __restrict__ gw1,
    const float* __restrict__ gb1, const float* __restrict__ g2,
    const float* __restrict__ g3, const float* __restrict__ g4,
    float* __restrict__ wq, bf16_t* __restrict__ wpack)
{
    int blk = blockIdx.x, t = threadIdx.x;
    {
        float acc = gb1[t];
        #pragma unroll
        for (int d = 0; d < 11; d++)
            acc = fmaf(q[blk * 11 + d], gw1[(52 + d) * 256 + t], acc);
        wq[blk * 256 + t] = acc;
    }
    for (int idx = blk * 3072 + t; idx < blk * 3072 + 3072; idx += 256) {
        int layer = idx >> 16;
        int rem = idx & 65535;
        int col = rem & 255;
        int k = rem >> 8;
        const float* gw = (layer == 0) ? g2 : ((layer == 1) ? g3 : g4);
        float v = gw[k * 256 + col];
        int cg = col >> 5, l31 = col & 31;
        int kt = k >> 4, l2 = (k >> 3) & 1, e = k & 7;
        int lane = l2 * 32 + l31;
        wpack[(((layer * 8 + cg) * 16 + kt) * 64 + lane) * 8 + e] = (bf16_t)v;
    }
}

// ---------------- finalize BN stats: one block per channel ----------------
__global__ __launch_bounds__(256) void fin_kernel(
    const float* __restrict__ part, int P, float inv_n,
    const float* __restrict__ gamma, const float* __restrict__ beta,
    float* __restrict__ scsh)
{
    int c = blockIdx.x;   // 24 channels
    int t = threadIdx.x;
    float s1 = 0.f, s2 = 0.f;
    for (int p = t; p < P; p += 256) {
        s1 += part[p * 48 + 2 * c];
        s2 += part[p * 48 + 2 * c + 1];
    }
    #pragma unroll
    for (int off = 32; off > 0; off >>= 1) {
        s1 += __shfl_xor(s1, off);
        s2 += __shfl_xor(s2, off);
    }
    __shared__ float r1[4], r2[4];
    int lane = t & 63, w = t >> 6;
    if (lane == 0) { r1[w] = s1; r2[w] = s2; }
    __syncthreads();
    if (t == 0) {
        float a1 = r1[0] + r1[1] + r1[2] + r1[3];
        float a2 = r2[0] + r2[1] + r2[2] + r2[3];
        float m = a1 * inv_n;
        float var = a2 * inv_n - m * m;
        float sc = gamma[c] * rsqrtf(var + EPS_BN);
        scsh[c] = sc;
        scsh[24 + c] = fmaf(-m, sc, beta[c]);
    }
}

// ---------------- unified conv: stride-2 3x3 + bias + relu (+BN-fold in) ---
template<int CIN, int HOUT, int OY_PER, int CO_PER, bool FOLD>
__global__ __launch_bounds__(256) void conv_kernel(
    const float* __restrict__ in, const float* __restrict__ scsh_in,
    const float* __restrict__ w, const float* __restrict__ bias,
    float* __restrict__ out, float* __restrict__ part_out)
{
    const int HIN = 2 * HOUT, ROWS = 2 * OY_PER + 3, RW = 2 * HOUT + 2;
    const int TILES = HOUT / OY_PER;
    const int WPC = (HOUT * OY_PER) / 64;      // waves per channel-group
    int b = blockIdx.x / TILES, tile = blockIdx.x % TILES;
    int oy0 = tile * OY_PER;
    __shared__ float tin[CIN][ROWS][RW];
    __shared__ float scf[24], shf[24];
    __shared__ float red[4][CO_PER * 2];
    int t = threadIdx.x;
    if (FOLD) {
        if (t < 24) { scf[t] = scsh_in[t]; shf[t] = scsh_in[24 + t]; }
        __syncthreads();
    }
    const int total = CIN * ROWS * RW;
    int iyb = 2 * oy0 - 1;
    #pragma unroll 2
    for (int idx = t; idx < total; idx += 256) {
        int rx = idx % RW;
        int rem = idx / RW;
        int ry = rem % ROWS;
        int ci = rem / ROWS;
        int iy = iyb + ry, ix = rx - 1;
        float v = 0.f;
        if ((unsigned)iy < (unsigned)HIN && (unsigned)ix < (unsigned)HIN) {
            float raw = in[(b * CIN + ci) * HIN * HIN + iy * HIN + ix];
            v = FOLD ? fmaf(raw, scf[ci], shf[ci]) : raw;
        }
        tin[ci][ry][rx] = v;
    }
    __syncthreads();
    int ox = t % HOUT;
    int oyl = (t / HOUT) % OY_PER;
    int cog = t / (HOUT * OY_PER);            // wave-uniform
    const float* wp = w + cog * CO_PER * CIN * 9;
    float acc[CO_PER];
    #pragma unroll
    for (int r = 0; r < CO_PER; r++) acc[r] = bias[cog * CO_PER + r];
    for (int ci = 0; ci < CIN; ci++)
        #pragma unroll
        for (int ky = 0; ky < 3; ky++)
            #pragma unroll
            for (int kx = 0; kx < 3; kx++) {
                float v = tin[ci][2 * oyl + ky][2 * ox + kx];
                #pragma unroll
                for (int r = 0; r < CO_PER; r++)
                    acc[r] = fmaf(v, wp[(r * CIN + ci) * 9 + ky * 3 + kx], acc[r]);
            }
    int oy = oy0 + oyl;
    float s1[CO_PER], s2[CO_PER];
    #pragma unroll
    for (int r = 0; r < CO_PER; r++) {
        float v = fmaxf(acc[r], 0.f);
        out[((b * 24 + cog * CO_PER + r) * HOUT + oy) * HOUT + ox] = v;
        s1[r] = v;
        s2[r] = v * v;
    }
    int lane = t & 63, w_id = t >> 6;
    #pragma unroll
    for (int r = 0; r < CO_PER; r++) {
        float a = s1[r], c2 = s2[r];
        #pragma unroll
        for (int off = 32; off > 0; off >>= 1) {
            a += __shfl_xor(a, off);
            c2 += __shfl_xor(c2, off);
        }
        if (lane == 0) { red[w_id][r * 2] = a; red[w_id][r * 2 + 1] = c2; }
    }
    __syncthreads();
    if (t < 48) {
        int ch = t >> 1, st = t & 1;
        int cg = ch / CO_PER, r = ch % CO_PER;
        float v = 0.f;
        #pragma unroll
        for (int k = 0; k < WPC; k++) v += red[cg * WPC + k][r * 2 + st];
        part_out[blockIdx.x * 48 + t] = v;
    }
}

// ---------------- U/V with BN4 folded (scale/shift precomputed) ------------
__global__ __launch_bounds__(256) void uv_kernel(
    const float* __restrict__ x4, const float* __restrict__ scsh4,
    const float* __restrict__ gw1, float* __restrict__ U, float* __restrict__ V)
{
    int b = blockIdx.x >> 2, n0 = (blockIdx.x & 3) * 16;
    __shared__ float o[16][26];
    int t = threadIdx.x;
    for (int idx = t; idx < 16 * 26; idx += 256) {
        int n = idx / 26, f = idx % 26;
        int ng = n0 + n;
        float val;
        if (f < 24)
            val = fmaf(x4[(b * 24 + f) * 64 + ng], scsh4[f], scsh4[24 + f]);
        else if (f == 24) val = (float)(ng >> 3) * 0.125f;
        else              val = (float)(ng & 7) * 0.125f;
        o[n][f] = val;
    }
    __syncthreads();
    float g1u[26], g1v[26];
    #pragma unroll
    for (int f = 0; f < 26; f++) {
        g1u[f] = gw1[f * 256 + t];
        g1v[f] = gw1[(26 + f) * 256 + t];
    }
    for (int n = 0; n < 16; n++) {
        float u = 0.f, v = 0.f;
        #pragma unroll
        for (int f = 0; f < 26; f++) {
            float of = o[n][f];
            u = fmaf(of, g1u[f], u);
            v = fmaf(of, g1v[f], v);
        }
        int ng = n0 + n;
        U[(b * 64 + ng) * 256 + t] = u;
        V[(b * 64 + ng) * 256 + t] = v;
    }
}

// ---------------- fused pair MLP: 256 thr, 4 waves, ONE i (64 rows) --------
// v6: 1 i-row-block per workgroup. hA = 33 KB -> 4 blocks/CU by LDS; acc
// halves to 64 AGPRs and W prefetch is 1-deep so combined regs fit 4
// waves/SIMD (__launch_bounds__(256,4)). W-L2 traffic doubles vs r4 (each
// block reads full W for 64 rows) — deliberately traded for 2x TLP so
// LDS/L2/VALU hide under the MFMA floor instead of serializing.
// Wave wn owns feats wn*64..+64 (2 cgs) and all 64 rows (mt=0..1).
__global__ __launch_bounds__(256, 4) void pair_kernel(
    const float* __restrict__ U, const float* __restrict__ V,
    const float* __restrict__ wq, const bf16_t* __restrict__ wpack,
    const float* __restrict__ gb2, const float* __restrict__ gb3,
    const float* __restrict__ gb4, float* __restrict__ partial)
{
    __shared__ __align__(16) bf16_t hA[64][264];
    int blk = blockIdx.x;
    int b = blk >> 6;
    int i0 = blk & 63;
    int t = threadIdx.x;

    // ---- build h1: thread covers 4 feats x 16 j, float4 loads + b64 LDS writes
    {
        int c4 = (t & 63) * 4;
        int jh = t >> 6;                  // 0..3
        float4 wq4 = *(const float4*)(wq + b * 256 + c4);
        float4 u0 = *(const float4*)(U + (b * 64 + i0) * 256 + c4);
        u0.x += wq4.x; u0.y += wq4.y; u0.z += wq4.z; u0.w += wq4.w;
        const float* Vb = V + (b * 64) * 256 + c4;
        for (int j = jh * 16; j < jh * 16 + 16; j++) {
            float4 v = *(const float4*)(Vb + j * 256);
            bf16x4 h0;
            h0[0] = (bf16_t)fmaxf(u0.x + v.x, 0.f);
            h0[1] = (bf16_t)fmaxf(u0.y + v.y, 0.f);
            h0[2] = (bf16_t)fmaxf(u0.z + v.z, 0.f);
            h0[3] = (bf16_t)fmaxf(u0.w + v.w, 0.f);
            *(bf16x4*)&hA[j][c4] = h0;
        }
    }
    __syncthreads();

    int lane = t & 63, wn = t >> 6;       // 4 waves
    int l31 = lane & 31, l2 = lane >> 5;

    // ======== layers 1,2: transposed-output, wave = 64 rows x 64 feats
    #pragma unroll 1
    for (int layer = 0; layer < 2; layer++) {
        const float* bias = (layer == 0) ? gb2 : gb3;
        const bf16_t* W0 = wpack + ((size_t)((layer * 8 + wn * 2) * 1024) + lane) * 8;
        const bf16_t* W1 = W0 + 8192;

        // bias folded into acc init: transposed D reg = out-feat
        floatx16 acc[2][2];
        #pragma unroll
        for (int nt = 0; nt < 2; nt++) {
            int fb = (wn * 2 + nt) * 32 + 4 * l2;
            #pragma unroll
            for (int g = 0; g < 4; g++) {
                float4 bv = *(const float4*)(bias + fb + 8 * g);
                acc[0][nt][4 * g + 0] = bv.x;
                acc[0][nt][4 * g + 1] = bv.y;
                acc[0][nt][4 * g + 2] = bv.z;
                acc[0][nt][4 * g + 3] = bv.w;
            }
            acc[1][nt] = acc[0][nt];
        }

        bf16x8 Wc[2], Wp[2];
        Wc[0] = *(const bf16x8*)W0;
        Wc[1] = *(const bf16x8*)W1;

        #pragma unroll
        for (int ks = 0; ks < 16; ks++) {
            if (ks < 15) {
                Wp[0] = *(const bf16x8*)(W0 + (ks + 1) * 512);
                Wp[1] = *(const bf16x8*)(W1 + (ks + 1) * 512);
            }
            bf16x8 h0 = *(const bf16x8*)&hA[l31][ks * 16 + l2 * 8];
            bf16x8 h1v = *(const bf16x8*)&hA[32 + l31][ks * 16 + l2 * 8];
            #pragma unroll
            for (int nt = 0; nt < 2; nt++) {
                acc[0][nt] = __builtin_amdgcn_mfma_f32_32x32x16_bf16(Wc[nt], h0, acc[0][nt], 0, 0, 0);
                acc[1][nt] = __builtin_amdgcn_mfma_f32_32x32x16_bf16(Wc[nt], h1v, acc[1][nt], 0, 0, 0);
            }
            if (ks < 15) { Wc[0] = Wp[0]; Wc[1] = Wp[1]; }
        }

        __syncthreads();
        // epilogue: D row = out-feat; regs 4g..4g+3 = 4 consecutive feats
        #pragma unroll
        for (int mt = 0; mt < 2; mt++) {
            int row = mt * 32 + l31;
            #pragma unroll
            for (int nt = 0; nt < 2; nt++) {
                int fb = (wn * 2 + nt) * 32 + 4 * l2;
                #pragma unroll
                for (int g = 0; g < 4; g++) {
                    bf16x4 w4;
                    w4[0] = (bf16_t)fmaxf(acc[mt][nt][4 * g + 0], 0.f);
                    w4[1] = (bf16_t)fmaxf(acc[mt][nt][4 * g + 1], 0.f);
                    w4[2] = (bf16_t)fmaxf(acc[mt][nt][4 * g + 2], 0.f);
                    w4[3] = (bf16_t)fmaxf(acc[mt][nt][4 * g + 3], 0.f);
                    *(bf16x4*)&hA[row][fb + 8 * g] = w4;
                }
            }
        }
        __syncthreads();
    }

    // ======== layer 3: untransposed (lane = out-col) + register reduction
    {
        floatx16 acc[2][2];
        #pragma unroll
        for (int nt = 0; nt < 2; nt++) {
            float bc = gb4[wn * 64 + nt * 32 + l31];
            #pragma unroll
            for (int mt = 0; mt < 2; mt++)
                #pragma unroll
                for (int reg = 0; reg < 16; reg++)
                    acc[mt][nt][reg] = bc;
        }

        const bf16_t* W0 = wpack + ((size_t)((16 + wn * 2) * 1024) + lane) * 8;
        const bf16_t* W1 = W0 + 8192;
        bf16x8 Wc[2], Wp[2];
        Wc[0] = *(const bf16x8*)W0;
        Wc[1] = *(const bf16x8*)W1;

        #pragma unroll
        for (int ks = 0; ks < 16; ks++) {
            if (ks < 15) {
                Wp[0] = *(const bf16x8*)(W0 + (ks + 1) * 512);
                Wp[1] = *(const bf16x8*)(W1 + (ks + 1) * 512);
            }
            bf16x8 a0 = *(const bf16x8*)&hA[l31][ks * 16 + l2 * 8];
            bf16x8 a1 = *(const bf16x8*)&hA[32 + l31][ks * 16 + l2 * 8];
            #pragma unroll
            for (int nt = 0; nt < 2; nt++) {
                acc[0][nt] = __builtin_amdgcn_mfma_f32_32x32x16_bf16(a0, Wc[nt], acc[0][nt], 0, 0, 0);
                acc[1][nt] = __builtin_amdgcn_mfma_f32_32x32x16_bf16(a1, Wc[nt], acc[1][nt], 0, 0, 0);
            }
            if (ks < 15) { Wc[0] = Wp[0]; Wc[1] = Wp[1]; }
        }

        #pragma unroll
        for (int nt = 0; nt < 2; nt++) {
            float s = 0.f;
            #pragma unroll
            for (int mt = 0; mt < 2; mt++)
                #pragma unroll
                for (int reg = 0; reg < 16; reg++)
                    s += fmaxf(acc[mt][nt][reg], 0.0f);
            s += __shfl_xor(s, 32);
            if (l2 == 0)
                partial[blk * 256 + wn * 64 + nt * 32 + l31] = s;
        }
    }
}

// ---------------- f_phi ----------------
__global__ __launch_bounds__(256) void fphi_kernel(
    const float* __restrict__ partial,
    const float* __restrict__ fw1, const float* __restrict__ fb1,
    const float* __restrict__ fw2, const float* __restrict__ fb2,
    const float* __restrict__ fw3, const float* __restrict__ fb3,
    float* __restrict__ out)
{
    int b = blockIdx.x, t = threadIdx.x;
    __shared__ float g[256], h1[256], h2[256];
    float s = 0.f;
    for (int k = 0; k < 64; k++) s += partial[(b * 64 + k) * 256 + t];
    g[t] = s * (1.0f / 4096.0f);
    __syncthreads();
    float a1 = fb1[t];
    for (int k = 0; k < 256; k++) a1 = fmaf(g[k], fw1[k * 256 + t], a1);
    h1[t] = fmaxf(a1, 0.0f);
    __syncthreads();
    float a2 = fb2[t];
    for (int k = 0; k < 256; k++) a2 = fmaf(h1[k], fw2[k * 256 + t], a2);
    h2[t] = fmaxf(a2, 0.0f);
    __syncthreads();
    if (t < 10) {
        float a3 = fb3[t];
        for (int k = 0; k < 256; k++) a3 = fmaf(h2[k], fw3[k * 10 + t], a3);
        out[b * 10 + t] = a3;
    }
}

extern "C" void kernel_launch(void* const* d_in, const int* in_sizes, int n_in,
                              void* d_out, int out_size, void* d_ws, size_t ws_size,
                              hipStream_t stream)
{
    (void)in_sizes; (void)n_in; (void)out_size; (void)ws_size;
    const float* img = (const float*)d_in[0];
    const float* q   = (const float*)d_in[1];
    const float* cw[4] = {(const float*)d_in[2],  (const float*)d_in[6],
                          (const float*)d_in[10], (const float*)d_in[14]};
    const float* cb[4] = {(const float*)d_in[3],  (const float*)d_in[7],
                          (const float*)d_in[11], (const float*)d_in[15]};
    const float* bg[4] = {(const float*)d_in[4],  (const float*)d_in[8],
                          (const float*)d_in[12], (const float*)d_in[16]};
    const float* bbv[4] = {(const float*)d_in[5],  (const float*)d_in[9],
                           (const float*)d_in[13], (const float*)d_in[17]};
    const float* gw1 = (const float*)d_in[18]; const float* gb1 = (const float*)d_in[19];
    const float* gw2 = (const float*)d_in[20]; const float* gb2 = (const float*)d_in[21];
    const float* gw3 = (const float*)d_in[22]; const float* gb3 = (const float*)d_in[23];
    const float* gw4 = (const float*)d_in[24]; const float* gb4 = (const float*)d_in[25];
    const float* fw1 = (const float*)d_in[26]; const float* fb1 = (const float*)d_in[27];
    const float* fw2 = (const float*)d_in[28]; const float* fb2 = (const float*)d_in[29];
    const float* fw3 = (const float*)d_in[30]; const float* fb3 = (const float*)d_in[31];

    float* ws  = (float*)d_ws;
    float* x1  = ws;                      // 6291456 (dead after conv2 -> reused as pair partial)
    float* x2  = x1 + 6291456;            // 1572864
    float* x3  = x2 + 1572864;            // 393216
    float* x4  = x3 + 393216;             // 98304
    float* U   = x4 + 98304;              // 1048576
    float* V   = U + 1048576;             // 1048576
    float* wqv = V + 1048576;             // 16384
    float* part_unused = wqv + 16384;     // (old slot, kept for layout stability)
    float* p1  = part_unused + 524288;    // 2048*48
    float* p2  = p1 + 98304;              // 1024*48
    float* p3  = p2 + 49152;              // 256*48
    float* p4  = p3 + 12288;              // 64*48
    float* scsh1 = p4 + 3072;
    float* scsh2 = scsh1 + 48;
    float* scsh3 = scsh2 + 48;
    float* scsh4 = scsh3 + 48;
    bf16_t* wpack = (bf16_t*)(scsh4 + 48);  // 3*65536 bf16
    float* part = x1;                     // 4096*256 floats = 1048576, fits in x1

    prep_kernel<<<64, 256, 0, stream>>>(q, gw1, gb1, gw2, gw3, gw4, wqv, wpack);
    conv_kernel<3, 64, 2, 12, false><<<2048, 256, 0, stream>>>(
        img, nullptr, cw[0], cb[0], x1, p1);
    fin_kernel<<<24, 256, 0, stream>>>(p1, 2048, 1.f / 262144.f, bg[0], bbv[0], scsh1);
    conv_kernel<24, 32, 2, 6, true><<<1024, 256, 0, stream>>>(
        x1, scsh1, cw[1], cb[1], x2, p2);
    fin_kernel<<<24, 256, 0, stream>>>(p2, 1024, 1.f / 65536.f, bg[1], bbv[1], scsh2);
    conv_kernel<24, 16, 4, 6, true><<<256, 256, 0, stream>>>(
        x2, scsh2, cw[2], cb[2], x3, p3);
    fin_kernel<<<24, 256, 0, stream>>>(p3, 256, 1.f / 16384.f, bg[2], bbv[2], scsh3);
    conv_kernel<24, 8, 8, 6, true><<<64, 256, 0, stream>>>(
        x3, scsh3, cw[3], cb[3], x4, p4);
    fin_kernel<<<24, 256, 0, stream>>>(p4, 64, 1.f / 4096.f, bg[3], bbv[3], scsh4);
    uv_kernel<<<256, 256, 0, stream>>>(x4, scsh4, gw1, U, V);
    pair_kernel<<<4096, 256, 0, stream>>>(U, V, wqv, wpack, gb2, gb3, gb4, part);
    fphi_kernel<<<64, 256, 0, stream>>>(part, fw1, fb1, fw2, fb2, fw3, fb3,
                                        (float*)d_out);
}

// Round 7
// 394.837 us; speedup vs baseline: 1.9765x; 1.0734x over previous
//
#include <hip/hip_runtime.h>
#include <hip/hip_bf16.h>

#define EPS_BN 1e-5f

typedef __bf16 bf16_t;
typedef __bf16 bf16x4 __attribute__((ext_vector_type(4)));
typedef __bf16 bf16x8 __attribute__((ext_vector_type(8)));
typedef float floatx16 __attribute__((ext_vector_type(16)));

// ---------------- unified conv: stride-2 3x3 + bias + relu (+BN-fold in) ---
// Launch-count fusion (no device fences — ordering comes from kernel
// boundaries only):
//  * PREP (conv1 only): blocks >= CONVBLKS run the prep body (wq build +
//    wpack packing) — replaces the prep_kernel launch.
//  * BN stats: each conv block atomicAdds its 48 partial sums into an 8-copy
//    accumulator (bnsum_out, 384 floats; copy = blockIdx&7 to cut contention).
//    The CONSUMER kernel (next conv / uv) reduces the 8 copies and computes
//    scale/shift in its prologue — replaces the 4 fin_kernel launches.
//    Accumulators re-zeroed each replay by one 6KB hipMemsetAsync.
template<int CIN, int HOUT, int OY_PER, int CO_PER, bool FOLD, bool PREP>
__global__ __launch_bounds__(256) void conv_kernel(
    const float* __restrict__ in,
    const float* __restrict__ bnsum_in, const float* __restrict__ gamma_in,
    const float* __restrict__ beta_in,
    const float* __restrict__ w, const float* __restrict__ bias,
    float* __restrict__ out, float* __restrict__ bnsum_out,
    const float* __restrict__ qv, const float* __restrict__ gw1v,
    const float* __restrict__ gb1v, const float* __restrict__ g2v,
    const float* __restrict__ g3v, const float* __restrict__ g4v,
    float* __restrict__ wqo, bf16_t* __restrict__ wpck)
{
    const int HIN = 2 * HOUT, ROWS = 2 * OY_PER + 3, RW = 2 * HOUT + 2;
    const int TILES = HOUT / OY_PER;
    const int CONVBLKS = 64 * TILES;          // B = 64
    const int WPC = (HOUT * OY_PER) / 64;     // waves per channel-group
    int t = threadIdx.x;

    if (PREP && blockIdx.x >= CONVBLKS) {
        // ---- embedded prep: wq + pack W fragments
        // wpack layout: (((layer*8+cg)*16+kt)*64+lane)*8+e ; serves as both
        // B-operand (untransposed) and A-operand (transposed) fragments.
        int blk = blockIdx.x - CONVBLKS;
        float acc = gb1v[t];
        #pragma unroll
        for (int d = 0; d < 11; d++)
            acc = fmaf(qv[blk * 11 + d], gw1v[(52 + d) * 256 + t], acc);
        wqo[blk * 256 + t] = acc;
        for (int idx = blk * 3072 + t; idx < blk * 3072 + 3072; idx += 256) {
            int layer = idx >> 16;
            int rem = idx & 65535;
            int col = rem & 255;
            int k = rem >> 8;
            const float* gw = (layer == 0) ? g2v : ((layer == 1) ? g3v : g4v);
            float v = gw[k * 256 + col];
            int cg = col >> 5, l31x = col & 31;
            int kt = k >> 4, l2x = (k >> 3) & 1, e = k & 7;
            int lane2 = l2x * 32 + l31x;
            wpck[(((layer * 8 + cg) * 16 + kt) * 64 + lane2) * 8 + e] = (bf16_t)v;
        }
        return;
    }

    int b = blockIdx.x / TILES, tile = blockIdx.x % TILES;
    int oy0 = tile * OY_PER;
    __shared__ float tin[CIN][ROWS][RW];
    __shared__ float scf[24], shf[24];
    __shared__ float red[4][CO_PER * 2];
    if (FOLD) {
        // BN finalize of the producer layer, from the 8-copy atomic sums
        if (t < 24) {
            float s1 = 0.f, s2 = 0.f;
            #pragma unroll
            for (int c = 0; c < 8; c++) {
                s1 += bnsum_in[c * 48 + 2 * t];
                s2 += bnsum_in[c * 48 + 2 * t + 1];
            }
            const float inv_n = 1.f / (float)(64 * HIN * HIN);
            float m = s1 * inv_n;
            float var = s2 * inv_n - m * m;
            float sc = gamma_in[t] * rsqrtf(var + EPS_BN);
            scf[t] = sc;
            shf[t] = fmaf(-m, sc, beta_in[t]);
        }
        __syncthreads();
    }
    const int total = CIN * ROWS * RW;
    int iyb = 2 * oy0 - 1;
    #pragma unroll 2
    for (int idx = t; idx < total; idx += 256) {
        int rx = idx % RW;
        int rem = idx / RW;
        int ry = rem % ROWS;
        int ci = rem / ROWS;
        int iy = iyb + ry, ix = rx - 1;
        float v = 0.f;
        if ((unsigned)iy < (unsigned)HIN && (unsigned)ix < (unsigned)HIN) {
            float raw = in[(b * CIN + ci) * HIN * HIN + iy * HIN + ix];
            v = FOLD ? fmaf(raw, scf[ci], shf[ci]) : raw;
        }
        tin[ci][ry][rx] = v;
    }
    __syncthreads();
    int ox = t % HOUT;
    int oyl = (t / HOUT) % OY_PER;
    int cog = t / (HOUT * OY_PER);            // wave-uniform
    const float* wp = w + cog * CO_PER * CIN * 9;
    float acc[CO_PER];
    #pragma unroll
    for (int r = 0; r < CO_PER; r++) acc[r] = bias[cog * CO_PER + r];
    for (int ci = 0; ci < CIN; ci++)
        #pragma unroll
        for (int ky = 0; ky < 3; ky++)
            #pragma unroll
            for (int kx = 0; kx < 3; kx++) {
                float v = tin[ci][2 * oyl + ky][2 * ox + kx];
                #pragma unroll
                for (int r = 0; r < CO_PER; r++)
                    acc[r] = fmaf(v, wp[(r * CIN + ci) * 9 + ky * 3 + kx], acc[r]);
            }
    int oy = oy0 + oyl;
    float s1[CO_PER], s2[CO_PER];
    #pragma unroll
    for (int r = 0; r < CO_PER; r++) {
        float v = fmaxf(acc[r], 0.f);
        out[((b * 24 + cog * CO_PER + r) * HOUT + oy) * HOUT + ox] = v;
        s1[r] = v;
        s2[r] = v * v;
    }
    int lane = t & 63, w_id = t >> 6;
    #pragma unroll
    for (int r = 0; r < CO_PER; r++) {
        float a = s1[r], c2 = s2[r];
        #pragma unroll
        for (int off = 32; off > 0; off >>= 1) {
            a += __shfl_xor(a, off);
            c2 += __shfl_xor(c2, off);
        }
        if (lane == 0) { red[w_id][r * 2] = a; red[w_id][r * 2 + 1] = c2; }
    }
    __syncthreads();
    if (t < 48) {
        int ch = t >> 1, st = t & 1;
        int cg = ch / CO_PER, r = ch % CO_PER;
        float v = 0.f;
        #pragma unroll
        for (int k = 0; k < WPC; k++) v += red[cg * WPC + k][r * 2 + st];
        atomicAdd(&bnsum_out[(blockIdx.x & 7) * 48 + t], v);
    }
}

// ---------------- U/V with BN4 finalize fused in prologue ------------------
__global__ __launch_bounds__(256) void uv_kernel(
    const float* __restrict__ x4, const float* __restrict__ bnsum4,
    const float* __restrict__ gamma4, const float* __restrict__ beta4,
    const float* __restrict__ gw1, float* __restrict__ U, float* __restrict__ V)
{
    int b = blockIdx.x >> 2, n0 = (blockIdx.x & 3) * 16;
    __shared__ float o[16][26];
    __shared__ float scf[24], shf[24];
    int t = threadIdx.x;
    if (t < 24) {
        float s1 = 0.f, s2 = 0.f;
        #pragma unroll
        for (int c = 0; c < 8; c++) {
            s1 += bnsum4[c * 48 + 2 * t];
            s2 += bnsum4[c * 48 + 2 * t + 1];
        }
        const float inv_n = 1.f / 4096.f;
        float m = s1 * inv_n;
        float var = s2 * inv_n - m * m;
        float sc = gamma4[t] * rsqrtf(var + EPS_BN);
        scf[t] = sc;
        shf[t] = fmaf(-m, sc, beta4[t]);
    }
    __syncthreads();
    for (int idx = t; idx < 16 * 26; idx += 256) {
        int n = idx / 26, f = idx % 26;
        int ng = n0 + n;
        float val;
        if (f < 24)
            val = fmaf(x4[(b * 24 + f) * 64 + ng], scf[f], shf[f]);
        else if (f == 24) val = (float)(ng >> 3) * 0.125f;
        else              val = (float)(ng & 7) * 0.125f;
        o[n][f] = val;
    }
    __syncthreads();
    float g1u[26], g1v[26];
    #pragma unroll
    for (int f = 0; f < 26; f++) {
        g1u[f] = gw1[f * 256 + t];
        g1v[f] = gw1[(26 + f) * 256 + t];
    }
    for (int n = 0; n < 16; n++) {
        float u = 0.f, v = 0.f;
        #pragma unroll
        for (int f = 0; f < 26; f++) {
            float of = o[n][f];
            u = fmaf(of, g1u[f], u);
            v = fmaf(of, g1v[f], v);
        }
        int ng = n0 + n;
        U[(b * 64 + ng) * 256 + t] = u;
        V[(b * 64 + ng) * 256 + t] = v;
    }
}

// ---------------- fused pair MLP (round-4 best: 100.8us) -------------------
// 256 thr, 4 waves, 2 i's (128 rows). Wave wn owns feats wn*64..+64 and ALL
// 128 rows: W read once per block-layer. Layers 1-2 transposed product
// acc=mfma(W,h), bias in acc init. Software-pipelined ks-loop: W 4-deep
// register rotation, h 1-deep ping-pong.
__global__ __launch_bounds__(256, 2) void pair_kernel(
    const float* __restrict__ U, const float* __restrict__ V,
    const float* __restrict__ wq, const bf16_t* __restrict__ wpack,
    const float* __restrict__ gb2, const float* __restrict__ gb3,
    const float* __restrict__ gb4, float* __restrict__ partial)
{
    __shared__ __align__(16) bf16_t hA[128][264];
    int blk = blockIdx.x;
    int b = blk >> 5;
    int i0 = (blk & 31) * 2;
    int t = threadIdx.x;

    {
        int c4 = (t & 63) * 4;
        int jh = t >> 6;                  // 0..3
        float4 wq4 = *(const float4*)(wq + b * 256 + c4);
        float4 u0 = *(const float4*)(U + (b * 64 + i0) * 256 + c4);
        float4 u1 = *(const float4*)(U + (b * 64 + i0 + 1) * 256 + c4);
        u0.x += wq4.x; u0.y += wq4.y; u0.z += wq4.z; u0.w += wq4.w;
        u1.x += wq4.x; u1.y += wq4.y; u1.z += wq4.z; u1.w += wq4.w;
        const float* Vb = V + (b * 64) * 256 + c4;
        for (int j = jh * 16; j < jh * 16 + 16; j++) {
            float4 v = *(const float4*)(Vb + j * 256);
            bf16x4 h0, h1;
            h0[0] = (bf16_t)fmaxf(u0.x + v.x, 0.f);
            h0[1] = (bf16_t)fmaxf(u0.y + v.y, 0.f);
            h0[2] = (bf16_t)fmaxf(u0.z + v.z, 0.f);
            h0[3] = (bf16_t)fmaxf(u0.w + v.w, 0.f);
            h1[0] = (bf16_t)fmaxf(u1.x + v.x, 0.f);
            h1[1] = (bf16_t)fmaxf(u1.y + v.y, 0.f);
            h1[2] = (bf16_t)fmaxf(u1.z + v.z, 0.f);
            h1[3] = (bf16_t)fmaxf(u1.w + v.w, 0.f);
            *(bf16x4*)&hA[j][c4] = h0;
            *(bf16x4*)&hA[64 + j][c4] = h1;
        }
    }
    __syncthreads();

    int lane = t & 63, wn = t >> 6;       // 4 waves
    int l31 = lane & 31, l2 = lane >> 5;

    #pragma unroll 1
    for (int layer = 0; layer < 2; layer++) {
        const float* bias = (layer == 0) ? gb2 : gb3;
        const bf16_t* W0 = wpack + ((size_t)((layer * 8 + wn * 2) * 1024) + lane) * 8;
        const bf16_t* W1 = W0 + 8192;

        floatx16 acc[4][2];
        #pragma unroll
        for (int nt = 0; nt < 2; nt++) {
            int fb = (wn * 2 + nt) * 32 + 4 * l2;
            #pragma unroll
            for (int g = 0; g < 4; g++) {
                float4 bv = *(const float4*)(bias + fb + 8 * g);
                acc[0][nt][4 * g + 0] = bv.x;
                acc[0][nt][4 * g + 1] = bv.y;
                acc[0][nt][4 * g + 2] = bv.z;
                acc[0][nt][4 * g + 3] = bv.w;
            }
            #pragma unroll
            for (int mt = 1; mt < 4; mt++) acc[mt][nt] = acc[0][nt];
        }

        bf16x8 Wb0[4], Wb1[4];
        #pragma unroll
        for (int p = 0; p < 4; p++) {
            Wb0[p] = *(const bf16x8*)(W0 + p * 512);
            Wb1[p] = *(const bf16x8*)(W1 + p * 512);
        }
        bf16x8 hb[2][4];
        #pragma unroll
        for (int mt = 0; mt < 4; mt++)
            hb[0][mt] = *(const bf16x8*)&hA[mt * 32 + l31][l2 * 8];

        #pragma unroll
        for (int ks = 0; ks < 16; ks++) {
            if (ks < 15) {
                #pragma unroll
                for (int mt = 0; mt < 4; mt++)
                    hb[(ks + 1) & 1][mt] =
                        *(const bf16x8*)&hA[mt * 32 + l31][(ks + 1) * 16 + l2 * 8];
            }
            #pragma unroll
            for (int mt = 0; mt < 4; mt++) {
                acc[mt][0] = __builtin_amdgcn_mfma_f32_32x32x16_bf16(Wb0[ks & 3], hb[ks & 1][mt], acc[mt][0], 0, 0, 0);
                acc[mt][1] = __builtin_amdgcn_mfma_f32_32x32x16_bf16(Wb1[ks & 3], hb[ks & 1][mt], acc[mt][1], 0, 0, 0);
            }
            if (ks + 4 < 16) {
                Wb0[ks & 3] = *(const bf16x8*)(W0 + (ks + 4) * 512);
                Wb1[ks & 3] = *(const bf16x8*)(W1 + (ks + 4) * 512);
            }
        }

        __syncthreads();
        #pragma unroll
        for (int mt = 0; mt < 4; mt++) {
            int row = mt * 32 + l31;
            #pragma unroll
            for (int nt = 0; nt < 2; nt++) {
                int fb = (wn * 2 + nt) * 32 + 4 * l2;
                #pragma unroll
                for (int g = 0; g < 4; g++) {
                    bf16x4 w4;
                    w4[0] = (bf16_t)fmaxf(acc[mt][nt][4 * g + 0], 0.f);
                    w4[1] = (bf16_t)fmaxf(acc[mt][nt][4 * g + 1], 0.f);
                    w4[2] = (bf16_t)fmaxf(acc[mt][nt][4 * g + 2], 0.f);
                    w4[3] = (bf16_t)fmaxf(acc[mt][nt][4 * g + 3], 0.f);
                    *(bf16x4*)&hA[row][fb + 8 * g] = w4;
                }
            }
        }
        __syncthreads();
    }

    {
        floatx16 acc[4][2];
        #pragma unroll
        for (int nt = 0; nt < 2; nt++) {
            float bc = gb4[wn * 64 + nt * 32 + l31];
            #pragma unroll
            for (int mt = 0; mt < 4; mt++)
                #pragma unroll
                for (int reg = 0; reg < 16; reg++)
                    acc[mt][nt][reg] = bc;
        }

        const bf16_t* W0 = wpack + ((size_t)((16 + wn * 2) * 1024) + lane) * 8;
        const bf16_t* W1 = W0 + 8192;

        bf16x8 Wb0[4], Wb1[4];
        #pragma unroll
        for (int p = 0; p < 4; p++) {
            Wb0[p] = *(const bf16x8*)(W0 + p * 512);
            Wb1[p] = *(const bf16x8*)(W1 + p * 512);
        }
        bf16x8 hb[2][4];
        #pragma unroll
        for (int mt = 0; mt < 4; mt++)
            hb[0][mt] = *(const bf16x8*)&hA[mt * 32 + l31][l2 * 8];

        #pragma unroll
        for (int ks = 0; ks < 16; ks++) {
            if (ks < 15) {
                #pragma unroll
                for (int mt = 0; mt < 4; mt++)
                    hb[(ks + 1) & 1][mt] =
                        *(const bf16x8*)&hA[mt * 32 + l31][(ks + 1) * 16 + l2 * 8];
            }
            #pragma unroll
            for (int mt = 0; mt < 4; mt++) {
                acc[mt][0] = __builtin_amdgcn_mfma_f32_32x32x16_bf16(hb[ks & 1][mt], Wb0[ks & 3], acc[mt][0], 0, 0, 0);
                acc[mt][1] = __builtin_amdgcn_mfma_f32_32x32x16_bf16(hb[ks & 1][mt], Wb1[ks & 3], acc[mt][1], 0, 0, 0);
            }
            if (ks + 4 < 16) {
                Wb0[ks & 3] = *(const bf16x8*)(W0 + (ks + 4) * 512);
                Wb1[ks & 3] = *(const bf16x8*)(W1 + (ks + 4) * 512);
            }
        }

        #pragma unroll
        for (int nt = 0; nt < 2; nt++) {
            float s = 0.f;
            #pragma unroll
            for (int mt = 0; mt < 4; mt++)
                #pragma unroll
                for (int reg = 0; reg < 16; reg++)
                    s += fmaxf(acc[mt][nt][reg], 0.0f);
            s += __shfl_xor(s, 32);
            if (l2 == 0)
                partial[blk * 256 + wn * 64 + nt * 32 + l31] = s;
        }
    }
}

// ---------------- f_phi ----------------
__global__ __launch_bounds__(256) void fphi_kernel(
    const float* __restrict__ partial,
    const float* __restrict__ fw1, const float* __restrict__ fb1,
    const float* __restrict__ fw2, const float* __restrict__ fb2,
    const float* __restrict__ fw3, const float* __restrict__ fb3,
    float* __restrict__ out)
{
    int b = blockIdx.x, t = threadIdx.x;
    __shared__ float g[256], h1[256], h2[256];
    float s = 0.f;
    for (int k = 0; k < 32; k++) s += partial[(b * 32 + k) * 256 + t];
    g[t] = s * (1.0f / 4096.0f);
    __syncthreads();
    float a1 = fb1[t];
    for (int k = 0; k < 256; k++) a1 = fmaf(g[k], fw1[k * 256 + t], a1);
    h1[t] = fmaxf(a1, 0.0f);
    __syncthreads();
    float a2 = fb2[t];
    for (int k = 0; k < 256; k++) a2 = fmaf(h1[k], fw2[k * 256 + t], a2);
    h2[t] = fmaxf(a2, 0.0f);
    __syncthreads();
    if (t < 10) {
        float a3 = fb3[t];
        for (int k = 0; k < 256; k++) a3 = fmaf(h2[k], fw3[k * 10 + t], a3);
        out[b * 10 + t] = a3;
    }
}

extern "C" void kernel_launch(void* const* d_in, const int* in_sizes, int n_in,
                              void* d_out, int out_size, void* d_ws, size_t ws_size,
                              hipStream_t stream)
{
    (void)in_sizes; (void)n_in; (void)out_size; (void)ws_size;
    const float* img = (const float*)d_in[0];
    const float* q   = (const float*)d_in[1];
    const float* cw[4] = {(const float*)d_in[2],  (const float*)d_in[6],
                          (const float*)d_in[10], (const float*)d_in[14]};
    const float* cb[4] = {(const float*)d_in[3],  (const float*)d_in[7],
                          (const float*)d_in[11], (const float*)d_in[15]};
    const float* bg[4] = {(const float*)d_in[4],  (const float*)d_in[8],
                          (const float*)d_in[12], (const float*)d_in[16]};
    const float* bbv[4] = {(const float*)d_in[5],  (const float*)d_in[9],
                           (const float*)d_in[13], (const float*)d_in[17]};
    const float* gw1 = (const float*)d_in[18]; const float* gb1 = (const float*)d_in[19];
    const float* gw2 = (const float*)d_in[20]; const float* gb2 = (const float*)d_in[21];
    const float* gw3 = (const float*)d_in[22]; const float* gb3 = (const float*)d_in[23];
    const float* gw4 = (const float*)d_in[24]; const float* gb4 = (const float*)d_in[25];
    const float* fw1 = (const float*)d_in[26]; const float* fb1 = (const float*)d_in[27];
    const float* fw2 = (const float*)d_in[28]; const float* fb2 = (const float*)d_in[29];
    const float* fw3 = (const float*)d_in[30]; const float* fb3 = (const float*)d_in[31];

    float* ws  = (float*)d_ws;
    float* x1  = ws;                      // 6291456
    float* x2  = x1 + 6291456;            // 1572864
    float* x3  = x2 + 1572864;            // 393216
    float* x4  = x3 + 393216;             // 98304
    float* U   = x4 + 98304;              // 1048576
    float* V   = U + 1048576;             // 1048576
    float* wqv = V + 1048576;             // 16384
    float* part = wqv + 16384;            // 524288 (2048*256)
    float* p1  = part + 524288;           // legacy slots (unused)
    float* p2  = p1 + 98304;
    float* p3  = p2 + 49152;
    float* p4  = p3 + 12288;
    float* scsh1 = p4 + 3072;
    float* scsh2 = scsh1 + 48;
    float* scsh3 = scsh2 + 48;
    float* scsh4 = scsh3 + 48;
    bf16_t* wpack = (bf16_t*)(scsh4 + 48);  // 3*65536 bf16
    float* bnsum = (float*)(wpack + 196608); // 4 layers x 8 copies x 48
    float* bnsum1 = bnsum;
    float* bnsum2 = bnsum + 384;
    float* bnsum3 = bnsum + 768;
    float* bnsum4 = bnsum + 1152;

    hipMemsetAsync(bnsum, 0, 4 * 384 * sizeof(float), stream);

    conv_kernel<3, 64, 2, 12, false, true><<<2048 + 64, 256, 0, stream>>>(
        img, nullptr, nullptr, nullptr, cw[0], cb[0], x1, bnsum1,
        q, gw1, gb1, gw2, gw3, gw4, wqv, wpack);
    conv_kernel<24, 32, 2, 6, true, false><<<1024, 256, 0, stream>>>(
        x1, bnsum1, bg[0], bbv[0], cw[1], cb[1], x2, bnsum2,
        nullptr, nullptr, nullptr, nullptr, nullptr, nullptr, nullptr, nullptr);
    conv_kernel<24, 16, 4, 6, true, false><<<256, 256, 0, stream>>>(
        x2, bnsum2, bg[1], bbv[1], cw[2], cb[2], x3, bnsum3,
        nullptr, nullptr, nullptr, nullptr, nullptr, nullptr, nullptr, nullptr);
    conv_kernel<24, 8, 8, 6, true, false><<<64, 256, 0, stream>>>(
        x3, bnsum3, bg[2], bbv[2], cw[3], cb[3], x4, bnsum4,
        nullptr, nullptr, nullptr, nullptr, nullptr, nullptr, nullptr, nullptr);
    uv_kernel<<<256, 256, 0, stream>>>(x4, bnsum4, bg[3], bbv[3], gw1, U, V);
    pair_kernel<<<2048, 256, 0, stream>>>(U, V, wqv, wpack, gb2, gb3, gb4, part);
    fphi_kernel<<<64, 256, 0, stream>>>(part, fw1, fb1, fw2, fb2, fw3, fb3,
                                        (float*)d_out);
}

// Round 8
// 388.306 us; speedup vs baseline: 2.0097x; 1.0168x over previous
//
#include <hip/hip_runtime.h>
#include <hip/hip_bf16.h>

#define EPS_BN 1e-5f

typedef __bf16 bf16_t;
typedef __bf16 bf16x4 __attribute__((ext_vector_type(4)));
typedef __bf16 bf16x8 __attribute__((ext_vector_type(8)));
typedef float floatx16 __attribute__((ext_vector_type(16)));

// ---------------- unified conv: stride-2 3x3 + bias + relu (+BN-fold in) ---
// Launch-count fusion (no device fences — ordering comes from kernel
// boundaries only):
//  * PREP (conv1 only): blocks >= CONVBLKS run the prep body (wq build +
//    wpack packing) — replaces the prep_kernel launch.
//  * BN stats: each conv block atomicAdds its 48 partial sums into an 8-copy
//    accumulator (bnsum_out, 384 floats; copy = blockIdx&7 to cut contention).
//    The CONSUMER kernel (next conv / uv) reduces the 8 copies and computes
//    scale/shift in its prologue — replaces the 4 fin_kernel launches.
//    Accumulators re-zeroed each replay by one 6KB hipMemsetAsync.
template<int CIN, int HOUT, int OY_PER, int CO_PER, bool FOLD, bool PREP>
__global__ __launch_bounds__(256) void conv_kernel(
    const float* __restrict__ in,
    const float* __restrict__ bnsum_in, const float* __restrict__ gamma_in,
    const float* __restrict__ beta_in,
    const float* __restrict__ w, const float* __restrict__ bias,
    float* __restrict__ out, float* __restrict__ bnsum_out,
    const float* __restrict__ qv, const float* __restrict__ gw1v,
    const float* __restrict__ gb1v, const float* __restrict__ g2v,
    const float* __restrict__ g3v, const float* __restrict__ g4v,
    float* __restrict__ wqo, bf16_t* __restrict__ wpck)
{
    const int HIN = 2 * HOUT, ROWS = 2 * OY_PER + 3, RW = 2 * HOUT + 2;
    const int TILES = HOUT / OY_PER;
    const int CONVBLKS = 64 * TILES;          // B = 64
    const int WPC = (HOUT * OY_PER) / 64;     // waves per channel-group
    int t = threadIdx.x;

    if (PREP && blockIdx.x >= CONVBLKS) {
        // ---- embedded prep: wq + pack W fragments
        // wpack layout: (((layer*8+cg)*16+kt)*64+lane)*8+e ; serves as both
        // B-operand (untransposed) and A-operand (transposed) fragments.
        int blk = blockIdx.x - CONVBLKS;
        float acc = gb1v[t];
        #pragma unroll
        for (int d = 0; d < 11; d++)
            acc = fmaf(qv[blk * 11 + d], gw1v[(52 + d) * 256 + t], acc);
        wqo[blk * 256 + t] = acc;
        for (int idx = blk * 3072 + t; idx < blk * 3072 + 3072; idx += 256) {
            int layer = idx >> 16;
            int rem = idx & 65535;
            int col = rem & 255;
            int k = rem >> 8;
            const float* gw = (layer == 0) ? g2v : ((layer == 1) ? g3v : g4v);
            float v = gw[k * 256 + col];
            int cg = col >> 5, l31x = col & 31;
            int kt = k >> 4, l2x = (k >> 3) & 1, e = k & 7;
            int lane2 = l2x * 32 + l31x;
            wpck[(((layer * 8 + cg) * 16 + kt) * 64 + lane2) * 8 + e] = (bf16_t)v;
        }
        return;
    }

    int b = blockIdx.x / TILES, tile = blockIdx.x % TILES;
    int oy0 = tile * OY_PER;
    __shared__ float tin[CIN][ROWS][RW];
    __shared__ float scf[24], shf[24];
    __shared__ float red[4][CO_PER * 2];
    if (FOLD) {
        // BN finalize of the producer layer, from the 8-copy atomic sums
        if (t < 24) {
            float s1 = 0.f, s2 = 0.f;
            #pragma unroll
            for (int c = 0; c < 8; c++) {
                s1 += bnsum_in[c * 48 + 2 * t];
                s2 += bnsum_in[c * 48 + 2 * t + 1];
            }
            const float inv_n = 1.f / (float)(64 * HIN * HIN);
            float m = s1 * inv_n;
            float var = s2 * inv_n - m * m;
            float sc = gamma_in[t] * rsqrtf(var + EPS_BN);
            scf[t] = sc;
            shf[t] = fmaf(-m, sc, beta_in[t]);
        }
        __syncthreads();
    }
    const int total = CIN * ROWS * RW;
    int iyb = 2 * oy0 - 1;
    #pragma unroll 2
    for (int idx = t; idx < total; idx += 256) {
        int rx = idx % RW;
        int rem = idx / RW;
        int ry = rem % ROWS;
        int ci = rem / ROWS;
        int iy = iyb + ry, ix = rx - 1;
        float v = 0.f;
        if ((unsigned)iy < (unsigned)HIN && (unsigned)ix < (unsigned)HIN) {
            float raw = in[(b * CIN + ci) * HIN * HIN + iy * HIN + ix];
            v = FOLD ? fmaf(raw, scf[ci], shf[ci]) : raw;
        }
        tin[ci][ry][rx] = v;
    }
    __syncthreads();
    int ox = t % HOUT;
    int oyl = (t / HOUT) % OY_PER;
    int cog = t / (HOUT * OY_PER);            // wave-uniform
    const float* wp = w + cog * CO_PER * CIN * 9;
    float acc[CO_PER];
    #pragma unroll
    for (int r = 0; r < CO_PER; r++) acc[r] = bias[cog * CO_PER + r];
    for (int ci = 0; ci < CIN; ci++)
        #pragma unroll
        for (int ky = 0; ky < 3; ky++)
            #pragma unroll
            for (int kx = 0; kx < 3; kx++) {
                float v = tin[ci][2 * oyl + ky][2 * ox + kx];
                #pragma unroll
                for (int r = 0; r < CO_PER; r++)
                    acc[r] = fmaf(v, wp[(r * CIN + ci) * 9 + ky * 3 + kx], acc[r]);
            }
    int oy = oy0 + oyl;
    float s1[CO_PER], s2[CO_PER];
    #pragma unroll
    for (int r = 0; r < CO_PER; r++) {
        float v = fmaxf(acc[r], 0.f);
        out[((b * 24 + cog * CO_PER + r) * HOUT + oy) * HOUT + ox] = v;
        s1[r] = v;
        s2[r] = v * v;
    }
    int lane = t & 63, w_id = t >> 6;
    #pragma unroll
    for (int r = 0; r < CO_PER; r++) {
        float a = s1[r], c2 = s2[r];
        #pragma unroll
        for (int off = 32; off > 0; off >>= 1) {
            a += __shfl_xor(a, off);
            c2 += __shfl_xor(c2, off);
        }
        if (lane == 0) { red[w_id][r * 2] = a; red[w_id][r * 2 + 1] = c2; }
    }
    __syncthreads();
    if (t < 48) {
        int ch = t >> 1, st = t & 1;
        int cg = ch / CO_PER, r = ch % CO_PER;
        float v = 0.f;
        #pragma unroll
        for (int k = 0; k < WPC; k++) v += red[cg * WPC + k][r * 2 + st];
        atomicAdd(&bnsum_out[(blockIdx.x & 7) * 48 + t], v);
    }
}

// ---------------- U/V with BN4 finalize fused in prologue ------------------
__global__ __launch_bounds__(256) void uv_kernel(
    const float* __restrict__ x4, const float* __restrict__ bnsum4,
    const float* __restrict__ gamma4, const float* __restrict__ beta4,
    const float* __restrict__ gw1, float* __restrict__ U, float* __restrict__ V)
{
    int b = blockIdx.x >> 2, n0 = (blockIdx.x & 3) * 16;
    __shared__ float o[16][26];
    __shared__ float scf[24], shf[24];
    int t = threadIdx.x;
    if (t < 24) {
        float s1 = 0.f, s2 = 0.f;
        #pragma unroll
        for (int c = 0; c < 8; c++) {
            s1 += bnsum4[c * 48 + 2 * t];
            s2 += bnsum4[c * 48 + 2 * t + 1];
        }
        const float inv_n = 1.f / 4096.f;
        float m = s1 * inv_n;
        float var = s2 * inv_n - m * m;
        float sc = gamma4[t] * rsqrtf(var + EPS_BN);
        scf[t] = sc;
        shf[t] = fmaf(-m, sc, beta4[t]);
    }
    __syncthreads();
    for (int idx = t; idx < 16 * 26; idx += 256) {
        int n = idx / 26, f = idx % 26;
        int ng = n0 + n;
        float val;
        if (f < 24)
            val = fmaf(x4[(b * 24 + f) * 64 + ng], scf[f], shf[f]);
        else if (f == 24) val = (float)(ng >> 3) * 0.125f;
        else              val = (float)(ng & 7) * 0.125f;
        o[n][f] = val;
    }
    __syncthreads();
    float g1u[26], g1v[26];
    #pragma unroll
    for (int f = 0; f < 26; f++) {
        g1u[f] = gw1[f * 256 + t];
        g1v[f] = gw1[(26 + f) * 256 + t];
    }
    for (int n = 0; n < 16; n++) {
        float u = 0.f, v = 0.f;
        #pragma unroll
        for (int f = 0; f < 26; f++) {
            float of = o[n][f];
            u = fmaf(of, g1u[f], u);
            v = fmaf(of, g1v[f], v);
        }
        int ng = n0 + n;
        U[(b * 64 + ng) * 256 + t] = u;
        V[(b * 64 + ng) * 256 + t] = v;
    }
}

// ---------------- fused pair MLP: 256 thr, 4 waves, 2 i's (128 rows) -------
// r8: continuous cross-layer W pipeline — the 4-deep rotation never drains:
// layer-0 slots prefetched BEFORE the h1-build barrier; at ks=12..15 the
// refill slots load the NEXT layer's frags 0..3 (consume-before-refill makes
// slot reuse safe). No layer starts with a cold W pipeline. Plus T5
// s_setprio(1) around each 8-MFMA burst (2 blocks/CU at different phases =
// role diversity, the m190-null prerequisite).
__global__ __launch_bounds__(256, 2) void pair_kernel(
    const float* __restrict__ U, const float* __restrict__ V,
    const float* __restrict__ wq, const bf16_t* __restrict__ wpack,
    const float* __restrict__ gb2, const float* __restrict__ gb3,
    const float* __restrict__ gb4, float* __restrict__ partial)
{
    __shared__ __align__(16) bf16_t hA[128][264];
    int blk = blockIdx.x;
    int b = blk >> 5;
    int i0 = (blk & 31) * 2;
    int t = threadIdx.x;
    int lane = t & 63, wn = t >> 6;       // 4 waves
    int l31 = lane & 31, l2 = lane >> 5;

    // W base pointers for the 3 layers (cg = wn*2 + nt)
    const bf16_t* WA0 = wpack + ((size_t)((wn * 2) * 1024) + lane) * 8;          // layer0
    const bf16_t* WA1 = WA0 + 8192;
    const bf16_t* WB0 = wpack + ((size_t)((8 + wn * 2) * 1024) + lane) * 8;      // layer1
    const bf16_t* WB1 = WB0 + 8192;
    const bf16_t* WC0 = wpack + ((size_t)((16 + wn * 2) * 1024) + lane) * 8;     // layer2
    const bf16_t* WC1 = WC0 + 8192;

    // ---- W pipeline (4-deep, persists across layers): prefetch layer-0 now,
    // so the loads complete during the h1 build below.
    bf16x8 Wb0[4], Wb1[4];
    #pragma unroll
    for (int p = 0; p < 4; p++) {
        Wb0[p] = *(const bf16x8*)(WA0 + p * 512);
        Wb1[p] = *(const bf16x8*)(WA1 + p * 512);
    }

    // ---- build h1: thread covers 4 feats x 16 j x 2 i
    {
        int c4 = (t & 63) * 4;
        int jh = t >> 6;                  // 0..3
        float4 wq4 = *(const float4*)(wq + b * 256 + c4);
        float4 u0 = *(const float4*)(U + (b * 64 + i0) * 256 + c4);
        float4 u1 = *(const float4*)(U + (b * 64 + i0 + 1) * 256 + c4);
        u0.x += wq4.x; u0.y += wq4.y; u0.z += wq4.z; u0.w += wq4.w;
        u1.x += wq4.x; u1.y += wq4.y; u1.z += wq4.z; u1.w += wq4.w;
        const float* Vb = V + (b * 64) * 256 + c4;
        for (int j = jh * 16; j < jh * 16 + 16; j++) {
            float4 v = *(const float4*)(Vb + j * 256);
            bf16x4 h0, h1;
            h0[0] = (bf16_t)fmaxf(u0.x + v.x, 0.f);
            h0[1] = (bf16_t)fmaxf(u0.y + v.y, 0.f);
            h0[2] = (bf16_t)fmaxf(u0.z + v.z, 0.f);
            h0[3] = (bf16_t)fmaxf(u0.w + v.w, 0.f);
            h1[0] = (bf16_t)fmaxf(u1.x + v.x, 0.f);
            h1[1] = (bf16_t)fmaxf(u1.y + v.y, 0.f);
            h1[2] = (bf16_t)fmaxf(u1.z + v.z, 0.f);
            h1[3] = (bf16_t)fmaxf(u1.w + v.w, 0.f);
            *(bf16x4*)&hA[j][c4] = h0;
            *(bf16x4*)&hA[64 + j][c4] = h1;
        }
    }
    __syncthreads();

    bf16x8 hb[2][4];

    // ======== layers 0,1: transposed-output, wave = 128 rows x 64 feats
    #pragma unroll 1
    for (int layer = 0; layer < 2; layer++) {
        const float* bias = (layer == 0) ? gb2 : gb3;
        const bf16_t* R0 = (layer == 0) ? WA0 : WB0;   // refill (current layer)
        const bf16_t* R1 = (layer == 0) ? WA1 : WB1;
        const bf16_t* N0 = (layer == 0) ? WB0 : WC0;   // continuation (next)
        const bf16_t* N1 = (layer == 0) ? WB1 : WC1;

        floatx16 acc[4][2];
        #pragma unroll
        for (int nt = 0; nt < 2; nt++) {
            int fb = (wn * 2 + nt) * 32 + 4 * l2;
            #pragma unroll
            for (int g = 0; g < 4; g++) {
                float4 bv = *(const float4*)(bias + fb + 8 * g);
                acc[0][nt][4 * g + 0] = bv.x;
                acc[0][nt][4 * g + 1] = bv.y;
                acc[0][nt][4 * g + 2] = bv.z;
                acc[0][nt][4 * g + 3] = bv.w;
            }
            #pragma unroll
            for (int mt = 1; mt < 4; mt++) acc[mt][nt] = acc[0][nt];
        }

        #pragma unroll
        for (int mt = 0; mt < 4; mt++)
            hb[0][mt] = *(const bf16x8*)&hA[mt * 32 + l31][l2 * 8];

        #pragma unroll
        for (int ks = 0; ks < 16; ks++) {
            if (ks < 15) {
                #pragma unroll
                for (int mt = 0; mt < 4; mt++)
                    hb[(ks + 1) & 1][mt] =
                        *(const bf16x8*)&hA[mt * 32 + l31][(ks + 1) * 16 + l2 * 8];
            }
            __builtin_amdgcn_s_setprio(1);
            #pragma unroll
            for (int mt = 0; mt < 4; mt++) {
                acc[mt][0] = __builtin_amdgcn_mfma_f32_32x32x16_bf16(Wb0[ks & 3], hb[ks & 1][mt], acc[mt][0], 0, 0, 0);
                acc[mt][1] = __builtin_amdgcn_mfma_f32_32x32x16_bf16(Wb1[ks & 3], hb[ks & 1][mt], acc[mt][1], 0, 0, 0);
            }
            __builtin_amdgcn_s_setprio(0);
            if (ks + 4 < 16) {
                Wb0[ks & 3] = *(const bf16x8*)(R0 + (ks + 4) * 512);
                Wb1[ks & 3] = *(const bf16x8*)(R1 + (ks + 4) * 512);
            } else {
                Wb0[ks & 3] = *(const bf16x8*)(N0 + (ks + 4 - 16) * 512);
                Wb1[ks & 3] = *(const bf16x8*)(N1 + (ks + 4 - 16) * 512);
            }
        }

        __syncthreads();
        // epilogue: D row = out-feat; regs 4g..4g+3 = 4 consecutive feats
        #pragma unroll
        for (int mt = 0; mt < 4; mt++) {
            int row = mt * 32 + l31;
            #pragma unroll
            for (int nt = 0; nt < 2; nt++) {
                int fb = (wn * 2 + nt) * 32 + 4 * l2;
                #pragma unroll
                for (int g = 0; g < 4; g++) {
                    bf16x4 w4;
                    w4[0] = (bf16_t)fmaxf(acc[mt][nt][4 * g + 0], 0.f);
                    w4[1] = (bf16_t)fmaxf(acc[mt][nt][4 * g + 1], 0.f);
                    w4[2] = (bf16_t)fmaxf(acc[mt][nt][4 * g + 2], 0.f);
                    w4[3] = (bf16_t)fmaxf(acc[mt][nt][4 * g + 3], 0.f);
                    *(bf16x4*)&hA[row][fb + 8 * g] = w4;
                }
            }
        }
        __syncthreads();
    }

    // ======== layer 2: untransposed (lane = out-col) + register reduction
    // Wb slots already hold layer-2 frags 0..3 from layer 1's continuation.
    {
        floatx16 acc[4][2];
        #pragma unroll
        for (int nt = 0; nt < 2; nt++) {
            float bc = gb4[wn * 64 + nt * 32 + l31];
            #pragma unroll
            for (int mt = 0; mt < 4; mt++)
                #pragma unroll
                for (int reg = 0; reg < 16; reg++)
                    acc[mt][nt][reg] = bc;
        }

        #pragma unroll
        for (int mt = 0; mt < 4; mt++)
            hb[0][mt] = *(const bf16x8*)&hA[mt * 32 + l31][l2 * 8];

        #pragma unroll
        for (int ks = 0; ks < 16; ks++) {
            if (ks < 15) {
                #pragma unroll
                for (int mt = 0; mt < 4; mt++)
                    hb[(ks + 1) & 1][mt] =
                        *(const bf16x8*)&hA[mt * 32 + l31][(ks + 1) * 16 + l2 * 8];
            }
            __builtin_amdgcn_s_setprio(1);
            #pragma unroll
            for (int mt = 0; mt < 4; mt++) {
                acc[mt][0] = __builtin_amdgcn_mfma_f32_32x32x16_bf16(hb[ks & 1][mt], Wb0[ks & 3], acc[mt][0], 0, 0, 0);
                acc[mt][1] = __builtin_amdgcn_mfma_f32_32x32x16_bf16(hb[ks & 1][mt], Wb1[ks & 3], acc[mt][1], 0, 0, 0);
            }
            __builtin_amdgcn_s_setprio(0);
            if (ks + 4 < 16) {
                Wb0[ks & 3] = *(const bf16x8*)(WC0 + (ks + 4) * 512);
                Wb1[ks & 3] = *(const bf16x8*)(WC1 + (ks + 4) * 512);
            }
        }

        #pragma unroll
        for (int nt = 0; nt < 2; nt++) {
            float s = 0.f;
            #pragma unroll
            for (int mt = 0; mt < 4; mt++)
                #pragma unroll
                for (int reg = 0; reg < 16; reg++)
                    s += fmaxf(acc[mt][nt][reg], 0.0f);
            s += __shfl_xor(s, 32);
            if (l2 == 0)
                partial[blk * 256 + wn * 64 + nt * 32 + l31] = s;
        }
    }
}

// ---------------- f_phi ----------------
__global__ __launch_bounds__(256) void fphi_kernel(
    const float* __restrict__ partial,
    const float* __restrict__ fw1, const float* __restrict__ fb1,
    const float* __restrict__ fw2, const float* __restrict__ fb2,
    const float* __restrict__ fw3, const float* __restrict__ fb3,
    float* __restrict__ out)
{
    int b = blockIdx.x, t = threadIdx.x;
    __shared__ float g[256], h1[256], h2[256];
    float s = 0.f;
    for (int k = 0; k < 32; k++) s += partial[(b * 32 + k) * 256 + t];
    g[t] = s * (1.0f / 4096.0f);
    __syncthreads();
    float a1 = fb1[t];
    for (int k = 0; k < 256; k++) a1 = fmaf(g[k], fw1[k * 256 + t], a1);
    h1[t] = fmaxf(a1, 0.0f);
    __syncthreads();
    float a2 = fb2[t];
    for (int k = 0; k < 256; k++) a2 = fmaf(h1[k], fw2[k * 256 + t], a2);
    h2[t] = fmaxf(a2, 0.0f);
    __syncthreads();
    if (t < 10) {
        float a3 = fb3[t];
        for (int k = 0; k < 256; k++) a3 = fmaf(h2[k], fw3[k * 10 + t], a3);
        out[b * 10 + t] = a3;
    }
}

extern "C" void kernel_launch(void* const* d_in, const int* in_sizes, int n_in,
                              void* d_out, int out_size, void* d_ws, size_t ws_size,
                              hipStream_t stream)
{
    (void)in_sizes; (void)n_in; (void)out_size; (void)ws_size;
    const float* img = (const float*)d_in[0];
    const float* q   = (const float*)d_in[1];
    const float* cw[4] = {(const float*)d_in[2],  (const float*)d_in[6],
                          (const float*)d_in[10], (const float*)d_in[14]};
    const float* cb[4] = {(const float*)d_in[3],  (const float*)d_in[7],
                          (const float*)d_in[11], (const float*)d_in[15]};
    const float* bg[4] = {(const float*)d_in[4],  (const float*)d_in[8],
                          (const float*)d_in[12], (const float*)d_in[16]};
    const float* bbv[4] = {(const float*)d_in[5],  (const float*)d_in[9],
                           (const float*)d_in[13], (const float*)d_in[17]};
    const float* gw1 = (const float*)d_in[18]; const float* gb1 = (const float*)d_in[19];
    const float* gw2 = (const float*)d_in[20]; const float* gb2 = (const float*)d_in[21];
    const float* gw3 = (const float*)d_in[22]; const float* gb3 = (const float*)d_in[23];
    const float* gw4 = (const float*)d_in[24]; const float* gb4 = (const float*)d_in[25];
    const float* fw1 = (const float*)d_in[26]; const float* fb1 = (const float*)d_in[27];
    const float* fw2 = (const float*)d_in[28]; const float* fb2 = (const float*)d_in[29];
    const float* fw3 = (const float*)d_in[30]; const float* fb3 = (const float*)d_in[31];

    float* ws  = (float*)d_ws;
    float* x1  = ws;                      // 6291456
    float* x2  = x1 + 6291456;            // 1572864
    float* x3  = x2 + 1572864;            // 393216
    float* x4  = x3 + 393216;             // 98304
    float* U   = x4 + 98304;              // 1048576
    float* V   = U + 1048576;             // 1048576
    float* wqv = V + 1048576;             // 16384
    float* part = wqv + 16384;            // 524288 (2048*256)
    float* p1  = part + 524288;           // legacy slots (unused)
    float* p2  = p1 + 98304;
    float* p3  = p2 + 49152;
    float* p4  = p3 + 12288;
    float* scsh1 = p4 + 3072;
    float* scsh2 = scsh1 + 48;
    float* scsh3 = scsh2 + 48;
    float* scsh4 = scsh3 + 48;
    bf16_t* wpack = (bf16_t*)(scsh4 + 48);  // 3*65536 bf16
    float* bnsum = (float*)(wpack + 196608); // 4 layers x 8 copies x 48
    float* bnsum1 = bnsum;
    float* bnsum2 = bnsum + 384;
    float* bnsum3 = bnsum + 768;
    float* bnsum4 = bnsum + 1152;

    hipMemsetAsync(bnsum, 0, 4 * 384 * sizeof(float), stream);

    conv_kernel<3, 64, 2, 12, false, true><<<2048 + 64, 256, 0, stream>>>(
        img, nullptr, nullptr, nullptr, cw[0], cb[0], x1, bnsum1,
        q, gw1, gb1, gw2, gw3, gw4, wqv, wpack);
    conv_kernel<24, 32, 2, 6, true, false><<<1024, 256, 0, stream>>>(
        x1, bnsum1, bg[0], bbv[0], cw[1], cb[1], x2, bnsum2,
        nullptr, nullptr, nullptr, nullptr, nullptr, nullptr, nullptr, nullptr);
    conv_kernel<24, 16, 4, 6, true, false><<<256, 256, 0, stream>>>(
        x2, bnsum2, bg[1], bbv[1], cw[2], cb[2], x3, bnsum3,
        nullptr, nullptr, nullptr, nullptr, nullptr, nullptr, nullptr, nullptr);
    conv_kernel<24, 8, 8, 6, true, false><<<64, 256, 0, stream>>>(
        x3, bnsum3, bg[2], bbv[2], cw[3], cb[3], x4, bnsum4,
        nullptr, nullptr, nullptr, nullptr, nullptr, nullptr, nullptr, nullptr);
    uv_kernel<<<256, 256, 0, stream>>>(x4, bnsum4, bg[3], bbv[3], gw1, U, V);
    pair_kernel<<<2048, 256, 0, stream>>>(U, V, wqv, wpack, gb2, gb3, gb4, part);
    fphi_kernel<<<64, 256, 0, stream>>>(part, fw1, fb1, fw2, fb2, fw3, fb3,
                                        (float*)d_out);
}